// Round 5
// baseline (873.120 us; speedup 1.0000x reference)
//
#include <hip/hip_runtime.h>

#define F_IN  512
#define F_OUT 128
#define FBIN  32            // nodes per fine bin
#define EPB   4096          // edges per fill partition unit
#define C2MAX 1600          // max fine bins (N <= 51200)
#define CAPF  2048          // slab capacity per bin (mean ~1024, ~32 sigma headroom)
#define GRID  1024          // 4 blocks/CU x 256 CUs: LDS 4x26112=102KB<160KB,
                            // 16 waves/CU <= 32, VGPR<=128 via launch_bounds.
                            // 33% margin vs the 6/CU LDS cap -> co-residency safe.

typedef __attribute__((ext_vector_type(8))) short  short8;
typedef __attribute__((ext_vector_type(4))) float  floatx4;

__device__ __forceinline__ unsigned short f2bf(float f) {
    unsigned u = __float_as_uint(f);
    return (unsigned short)((u + 0x7FFF + ((u >> 16) & 1)) >> 16);  // RNE
}
__device__ __forceinline__ float bf2f(unsigned b) {
    return __uint_as_float(b << 16);
}

// Hand-rolled grid barrier: counters are memset to 0 before each launch
// (stream-ordered, graph-capture-safe). All threads fence (device scope ->
// cross-XCD L2 wb/inv); tid0 arrives via device-scope atomic and spins with
// sleep backoff. Requires all gridDim.x blocks co-resident (static GRID=1024
// = 4 blocks/CU, 33% under the LDS capacity limit).
__device__ __forceinline__ void grid_barrier(int* cnt, int G) {
    __threadfence();                         // release all our stores
    __syncthreads();
    if (threadIdx.x == 0) {
        atomicAdd(cnt, 1);
        while (atomicAdd(cnt, 0) < G) __builtin_amdgcn_s_sleep(8);
    }
    __syncthreads();
    __threadfence();                         // acquire (discard stale lines)
}

// ---------------------------------------------------------------------------
// One persistent kernel, three phases (bodies = round-3 proven code):
//   A: wt transpose-convert fp32[512][128] -> bf16[128][512]; zero cursors.
//   B: units 0..FB-1 = fill (LDS rank + batched cursor claim -> slab append);
//      units FB..FB+GB-1 = MFMA GEMM h = bf16(x) @ wt (2Mx2N waves).
//   C: fine_agg per 32-node bin, grid-stride.
// ---------------------------------------------------------------------------
__global__ __launch_bounds__(256, 4) void fused(
    const int* __restrict__ ei, const float* __restrict__ ew,
    const float* __restrict__ x, const float* __restrict__ w,
    const float* __restrict__ bias, float* __restrict__ out,
    unsigned short* __restrict__ h, unsigned short* __restrict__ wt,
    int* __restrict__ cursor, uint2* __restrict__ ent, int* __restrict__ bar,
    int N, int E, int C2, int FB, int GB)
{
    __shared__ __align__(16) char smem[(64 * 68 + 128 * 68) * 2];  // 26112 B
    const int tid = threadIdx.x;
    const int G   = (int)gridDim.x;

    // ---------------- phase A: wt convert + cursor zero ----------------
    {
        const int ZB = (C2 + 255) >> 8;
        for (int u = (int)blockIdx.x; u < 128 + ZB; u += G) {
            if (u < 128) {
                int g0 = u * 512 + tid;
                #pragma unroll
                for (int r = 0; r < 2; ++r) {
                    int gid = g0 + r * 256;
                    int n = gid >> 9, k = gid & 511;
                    wt[gid] = f2bf(w[(size_t)k * F_OUT + n]);
                }
            } else {
                int c = (u - 128) * 256 + tid;
                if (c < C2) cursor[c] = 0;
            }
        }
    }
    grid_barrier(&bar[0], G);

    // ---------------- phase B: fill || GEMM ----------------
    for (int u = (int)blockIdx.x; u < FB + GB; u += G) {
        if (u < FB) {
            // ----- fill (r3 verbatim) -----
            int* lh    = (int*)smem;            // [C2MAX]
            int* lbase = (int*)smem + C2MAX;    // [C2MAX]
            for (int c = tid; c < C2; c += 256) lh[c] = 0;
            __syncthreads();

            const int base = u * EPB;
            unsigned       mykey[EPB / 256];
            unsigned char  mydl[EPB / 256];
            short          mybin[EPB / 256];
            unsigned short myrank[EPB / 256];

            #pragma unroll
            for (int j = 0; j < EPB / 256; ++j) {
                int e = base + j * 256 + tid;
                mybin[j] = -1;
                if (e < E) {
                    int   src = ei[e];
                    int   dst = ei[E + e];
                    float wv  = ew[e];
                    int bin = dst >> 5;
                    mykey[j]  = (unsigned)src | ((unsigned)f2bf(wv) << 16);
                    mydl[j]   = (unsigned char)(dst & (FBIN - 1));
                    mybin[j]  = (short)bin;
                    myrank[j] = (unsigned short)atomicAdd(&lh[bin], 1);
                }
            }
            __syncthreads();
            for (int c = tid; c < C2; c += 256)
                if (lh[c] > 0) lbase[c] = atomicAdd(&cursor[c], lh[c]);
            __syncthreads();
            #pragma unroll
            for (int j = 0; j < EPB / 256; ++j) {
                if (mybin[j] >= 0) {
                    int o = lbase[mybin[j]] + myrank[j];
                    if (o < CAPF)                      // overflow -> slow path covers
                        ent[(size_t)(int)mybin[j] * CAPF + o] = make_uint2(mykey[j], mydl[j]);
                }
            }
            __syncthreads();                           // smem reuse guard
        } else {
            // ----- GEMM (r3 verbatim, m0 from unit id) -----
            unsigned short* sa = (unsigned short*)smem;       // [64][68]
            unsigned short* sb = sa + 64 * 68;                // [128][68]

            const int wave = tid >> 6, lane = tid & 63;
            const int wm   = wave >> 1, wn = wave & 1;        // 2M x 2N
            const int g    = lane >> 4, l16 = lane & 15;
            const int m0   = (u - FB) * 64;

            const int arow = tid >> 2, aq = tid & 3;
            const int brow = tid >> 1, bh = tid & 1;

            floatx4 acc[2][4];
            #pragma unroll
            for (int rt = 0; rt < 2; ++rt)
                #pragma unroll
                for (int nt = 0; nt < 4; ++nt) acc[rt][nt] = (floatx4)(0.f);

            const bool  avalid = (m0 + arow) < N;
            const float* xp = x + (size_t)(m0 + arow) * F_IN + aq * 16;
            const unsigned short* bp = wt + brow * F_IN + bh * 32;

            float4 ax[4];
            uint4  bv[4];
            #pragma unroll
            for (int i = 0; i < 4; ++i) ax[i] = make_float4(0.f, 0.f, 0.f, 0.f);
            if (avalid) {
                #pragma unroll
                for (int i = 0; i < 4; ++i) ax[i] = ((const float4*)xp)[i];
            }
            #pragma unroll
            for (int i = 0; i < 4; ++i) bv[i] = ((const uint4*)bp)[i];

            for (int s = 0; s < 8; ++s) {
                __syncthreads();
                #pragma unroll
                for (int i = 0; i < 4; ++i) {
                    ushort4 t;
                    t.x = f2bf(ax[i].x); t.y = f2bf(ax[i].y);
                    t.z = f2bf(ax[i].z); t.w = f2bf(ax[i].w);
                    *(ushort4*)&sa[arow * 68 + aq * 16 + i * 4] = t;
                }
                #pragma unroll
                for (int i = 0; i < 4; ++i) {
                    *(uint2*)&sb[brow * 68 + bh * 32 + i * 8]     = make_uint2(bv[i].x, bv[i].y);
                    *(uint2*)&sb[brow * 68 + bh * 32 + i * 8 + 4] = make_uint2(bv[i].z, bv[i].w);
                }
                if (s < 7) {
                    int k0n = (s + 1) * 64;
                    if (avalid) {
                        #pragma unroll
                        for (int i = 0; i < 4; ++i) ax[i] = ((const float4*)(xp + k0n))[i];
                    }
                    #pragma unroll
                    for (int i = 0; i < 4; ++i) bv[i] = ((const uint4*)(bp + k0n))[i];
                }
                __syncthreads();

                #pragma unroll
                for (int kc = 0; kc < 2; ++kc) {
                    union { ushort4 uu[2]; short8 v; } af[2];
                    #pragma unroll
                    for (int rt = 0; rt < 2; ++rt) {
                        int abase = (wm * 32 + rt * 16 + l16) * 68 + kc * 32 + g * 8;
                        af[rt].uu[0] = *(ushort4*)&sa[abase];
                        af[rt].uu[1] = *(ushort4*)&sa[abase + 4];
                    }
                    #pragma unroll
                    for (int nt = 0; nt < 4; ++nt) {
                        union { ushort4 uu[2]; short8 v; } bf;
                        int bbase = (wn * 64 + nt * 16 + l16) * 68 + kc * 32 + g * 8;
                        bf.uu[0] = *(ushort4*)&sb[bbase];
                        bf.uu[1] = *(ushort4*)&sb[bbase + 4];
                        #pragma unroll
                        for (int rt = 0; rt < 2; ++rt)
                            acc[rt][nt] = __builtin_amdgcn_mfma_f32_16x16x32_bf16(
                                af[rt].v, bf.v, acc[rt][nt], 0, 0, 0);
                    }
                }
            }

            #pragma unroll
            for (int rt = 0; rt < 2; ++rt) {
                #pragma unroll
                for (int nt = 0; nt < 4; ++nt) {
                    #pragma unroll
                    for (int r = 0; r < 4; ++r) {
                        int row = m0 + wm * 32 + rt * 16 + g * 4 + r;
                        int col = wn * 64 + nt * 16 + l16;
                        if (row < N) h[(size_t)row * F_OUT + col] = f2bf(acc[rt][nt][r]);
                    }
                }
            }
            __syncthreads();                           // smem reuse guard
        }
    }
    grid_barrier(&bar[1], G);

    // ---------------- phase C: fine_agg (r3 verbatim, grid-stride) ----------
    {
        unsigned* ssort = (unsigned*)smem;             // 8 KB
        int* lh   = (int*)(smem + CAPF * 4);
        int* lcur = lh + FBIN;
        int* sso  = lcur + FBIN;                       // [FBIN+1]

        const int wave = tid >> 6;
        const int lane = tid & 63;
        const int half = lane >> 5;                    // edge parity
        const int q    = lane & 31;                    // feats q*4 .. q*4+3
        const float4 bvb = *(const float4*)&bias[q * 4];

        for (int b = (int)blockIdx.x; b < C2; b += G) {
            const int raw = cursor[b];
            const int cnt = raw < CAPF ? raw : CAPF;
            const uint2* slab = ent + (size_t)b * CAPF;

            if (tid < FBIN) lh[tid] = 0;
            __syncthreads();

            for (int i = tid; i < cnt; i += 256)
                atomicAdd(&lh[(int)slab[i].y], 1);
            __syncthreads();

            if (wave == 0 && lane < FBIN) {
                int v = lh[lane];
                int orig = v;
                #pragma unroll
                for (int off = 1; off < FBIN; off <<= 1) {
                    int t = __shfl_up(v, off);
                    if (lane >= off) v += t;
                }
                sso[lane]  = v - orig;
                lcur[lane] = v - orig;
                if (lane == FBIN - 1) sso[FBIN] = v;
            }
            __syncthreads();

            if (raw <= CAPF) {
                for (int i = tid; i < cnt; i += 256) {
                    uint2 e = slab[i];
                    int r = atomicAdd(&lcur[(int)e.y], 1);
                    ssort[r] = e.x;
                }
                __syncthreads();

                #pragma unroll 1
                for (int t = 0; t < 8; ++t) {
                    int nd   = wave * 8 + t;
                    int node = b * FBIN + nd;
                    int s = sso[nd], e2 = sso[nd + 1];
                    float4 acc = make_float4(0.f, 0.f, 0.f, 0.f);
                    for (int i = s; i < e2; i += 8) {
                        #pragma unroll
                        for (int j = 0; j < 4; ++j) {
                            int idx = i + j * 2 + half;
                            unsigned bk = 0;
                            if (idx < e2) bk = ssort[idx];
                            float wgt = bf2f(bk >> 16);
                            uint2 hv = *(const uint2*)&h[(size_t)(bk & 0xFFFF) * F_OUT + q * 4];
                            acc.x += bf2f(hv.x & 0xFFFF) * wgt;
                            acc.y += bf2f(hv.x >> 16)    * wgt;
                            acc.z += bf2f(hv.y & 0xFFFF) * wgt;
                            acc.w += bf2f(hv.y >> 16)    * wgt;
                        }
                    }
                    acc.x += __shfl_xor(acc.x, 32);
                    acc.y += __shfl_xor(acc.y, 32);
                    acc.z += __shfl_xor(acc.z, 32);
                    acc.w += __shfl_xor(acc.w, 32);
                    if (half == 0 && node < N) {
                        float4 o;
                        o.x = fmaxf(acc.x + bvb.x, 0.f);
                        o.y = fmaxf(acc.y + bvb.y, 0.f);
                        o.z = fmaxf(acc.z + bvb.z, 0.f);
                        o.w = fmaxf(acc.w + bvb.w, 0.f);
                        *(float4*)&out[(size_t)node * F_OUT + q * 4] = o;
                    }
                }
            } else {
                // slab overflow: correct-but-slow path over the raw edge list
                #pragma unroll 1
                for (int t = 0; t < 8; ++t) {
                    int nd   = wave * 8 + t;
                    int node = b * FBIN + nd;
                    float4 acc = make_float4(0.f, 0.f, 0.f, 0.f);
                    for (int e = half; e < E; e += 2) {
                        if (ei[E + e] == node) {
                            float wgt = ew[e];
                            uint2 hv = *(const uint2*)&h[(size_t)ei[e] * F_OUT + q * 4];
                            acc.x += bf2f(hv.x & 0xFFFF) * wgt;
                            acc.y += bf2f(hv.x >> 16)    * wgt;
                            acc.z += bf2f(hv.y & 0xFFFF) * wgt;
                            acc.w += bf2f(hv.y >> 16)    * wgt;
                        }
                    }
                    acc.x += __shfl_xor(acc.x, 32);
                    acc.y += __shfl_xor(acc.y, 32);
                    acc.z += __shfl_xor(acc.z, 32);
                    acc.w += __shfl_xor(acc.w, 32);
                    if (half == 0 && node < N) {
                        float4 o;
                        o.x = fmaxf(acc.x + bvb.x, 0.f);
                        o.y = fmaxf(acc.y + bvb.y, 0.f);
                        o.z = fmaxf(acc.z + bvb.z, 0.f);
                        o.w = fmaxf(acc.w + bvb.w, 0.f);
                        *(float4*)&out[(size_t)node * F_OUT + q * 4] = o;
                    }
                }
            }
            __syncthreads();                           // smem reuse guard
        }
    }
}

static inline size_t align256(size_t x) { return (x + 255) & ~(size_t)255; }

extern "C" void kernel_launch(void* const* d_in, const int* in_sizes, int n_in,
                              void* d_out, int out_size, void* d_ws, size_t ws_size,
                              hipStream_t stream)
{
    const float* x    = (const float*)d_in[0];   // [N, 512]
    const int*   ei   = (const int*)  d_in[1];   // [2, E] int32
    const float* ew   = (const float*)d_in[2];   // [E]
    const float* w    = (const float*)d_in[3];   // [512, 128]
    const float* bias = (const float*)d_in[4];   // [128]
    float*       out  = (float*)d_out;           // [N, 128]

    const int N  = in_sizes[0] / F_IN;           // 50000
    const int E  = in_sizes[2];                  // 1600000
    const int C2 = (N + FBIN - 1) / FBIN;        // 1563 fine bins

    // workspace layout (~38.6 MB)
    char*  ws = (char*)d_ws;
    size_t off = 0;
    unsigned short* h      = (unsigned short*)(ws + off); off += align256((size_t)N * F_OUT * 2);
    unsigned short* wt     = (unsigned short*)(ws + off); off += align256((size_t)F_OUT * F_IN * 2);
    int*            cursor = (int*)(ws + off);            off += align256((size_t)C2 * 4);
    int*            bar    = (int*)(ws + off);            off += align256(2 * sizeof(int));
    uint2*          ent    = (uint2*)(ws + off);          off += align256((size_t)C2 * CAPF * 8);

    const int FB = (E + EPB - 1) / EPB;          // 391 fill units
    const int GB = (N + 63) / 64;                // 782 gemm units

    // Only stream-ordered ops below (graph-capture-safe): memset + launch.
    (void)hipMemsetAsync(bar, 0, 2 * sizeof(int), stream);
    fused<<<GRID, 256, 0, stream>>>(ei, ew, x, w, bias, out, h, wt, cursor, ent,
                                    bar, N, E, C2, FB, GB);
}

// Round 6
// 254.040 us; speedup vs baseline: 3.4369x; 3.4369x over previous
//
#include <hip/hip_runtime.h>

#define F_IN  512
#define F_OUT 128
#define FBIN  32            // nodes per fine bin
#define EPB   4096          // edges per fill partition block
#define C2MAX 1600          // max fine bins (N <= 51200)
#define CAPF  2048          // slab capacity per bin (mean ~1024, ~32 sigma headroom)

typedef __attribute__((ext_vector_type(8))) short  short8;
typedef __attribute__((ext_vector_type(4))) float  floatx4;

__device__ __forceinline__ unsigned short f2bf(float f) {
    unsigned u = __float_as_uint(f);
    return (unsigned short)((u + 0x7FFF + ((u >> 16) & 1)) >> 16);  // RNE
}
__device__ __forceinline__ float bf2f(unsigned b) {
    return __uint_as_float(b << 16);
}

// ---------------------------------------------------------------------------
// prep: blocks 0..127 transpose-convert w fp32 [512][128] -> wt bf16 [128][512];
// blocks 128.. zero the per-bin cursors.
// ---------------------------------------------------------------------------
__global__ __launch_bounds__(256) void prep(
    const float* __restrict__ w, unsigned short* __restrict__ wt,
    int* __restrict__ cursor, int C2)
{
    const int tid = threadIdx.x;
    if ((int)blockIdx.x < 128) {
        int g0 = blockIdx.x * 512 + tid;
        #pragma unroll
        for (int r = 0; r < 2; ++r) {
            int gid = g0 + r * 256;
            int n = gid >> 9, k = gid & 511;
            wt[gid] = f2bf(w[(size_t)k * F_OUT + n]);
        }
    } else {
        int c = ((int)blockIdx.x - 128) * 256 + tid;
        if (c < C2) cursor[c] = 0;
    }
}

// ---------------------------------------------------------------------------
// fill_gemm: blocks 0..FB-1 = fill (register-staged one-pass, LDS rank +
// one batched cursor claim per bin -> slab append); blocks FB.. = MFMA GEMM
// h = bf16(x) @ wt, 16x16x32 MFMA, 2Mx2N waves (r3 body).
// ROUND-6 single change on this kernel: __launch_bounds__(256,2) -> (256,1).
// r0-r3 reported VGPR_Count=56 while the GEMM branch holds ~90+ live VGPRs
// (acc 32 + ax 16 + bv 16 + frags + addressing) -> suspected allocator cap
// at the 8-waves/EU budget (<=64 VGPR) with scratch spills in the stage loop.
// (256,1) allows up to 512 VGPR; expected VGPR ~96-110, no spill.
// ---------------------------------------------------------------------------
__global__ __launch_bounds__(256, 1) void fill_gemm(
    const int* __restrict__ ei, const float* __restrict__ ew,
    int* __restrict__ cursor, uint2* __restrict__ ent, int E, int C2, int FB,
    const float* __restrict__ x, const unsigned short* __restrict__ wt,
    unsigned short* __restrict__ h, int N)
{
    __shared__ __align__(16) char smem[(64 * 68 + 128 * 68) * 2];  // 26112 B
    const int tid = threadIdx.x;

    if ((int)blockIdx.x < FB) {
        // ----- fill (r3 verbatim) -----
        int* lh    = (int*)smem;            // [C2MAX]
        int* lbase = (int*)smem + C2MAX;    // [C2MAX]
        for (int c = tid; c < C2; c += 256) lh[c] = 0;
        __syncthreads();

        const int base = blockIdx.x * EPB;
        unsigned       mykey[EPB / 256];
        unsigned char  mydl[EPB / 256];
        short          mybin[EPB / 256];
        unsigned short myrank[EPB / 256];

        #pragma unroll
        for (int j = 0; j < EPB / 256; ++j) {
            int e = base + j * 256 + tid;
            mybin[j] = -1;
            if (e < E) {
                int   src = ei[e];
                int   dst = ei[E + e];
                float w   = ew[e];
                int bin = dst >> 5;                       // 32-node fine bin
                mykey[j]  = (unsigned)src | ((unsigned)f2bf(w) << 16);
                mydl[j]   = (unsigned char)(dst & (FBIN - 1));
                mybin[j]  = (short)bin;
                myrank[j] = (unsigned short)atomicAdd(&lh[bin], 1);
            }
        }
        __syncthreads();
        for (int c = tid; c < C2; c += 256)
            if (lh[c] > 0) lbase[c] = atomicAdd(&cursor[c], lh[c]);
        __syncthreads();
        #pragma unroll
        for (int j = 0; j < EPB / 256; ++j) {
            if (mybin[j] >= 0) {
                int o = lbase[mybin[j]] + myrank[j];
                if (o < CAPF)                              // overflow -> slow path covers
                    ent[(size_t)(int)mybin[j] * CAPF + o] = make_uint2(mykey[j], mydl[j]);
            }
        }
        return;
    }

    // ----- GEMM (r3 verbatim) -----
    unsigned short* sa = (unsigned short*)smem;       // [64][68]
    unsigned short* sb = sa + 64 * 68;                // [128][68]

    const int wave = tid >> 6, lane = tid & 63;
    const int wm   = wave >> 1, wn = wave & 1;        // 2M x 2N wave grid
    const int g    = lane >> 4, l16 = lane & 15;
    const int m0   = ((int)blockIdx.x - FB) * 64;

    const int arow = tid >> 2, aq = tid & 3;
    const int brow = tid >> 1, bh = tid & 1;

    floatx4 acc[2][4];
    #pragma unroll
    for (int rt = 0; rt < 2; ++rt)
        #pragma unroll
        for (int nt = 0; nt < 4; ++nt) acc[rt][nt] = (floatx4)(0.f);

    const bool  avalid = (m0 + arow) < N;
    const float* xp = x + (size_t)(m0 + arow) * F_IN + aq * 16;
    const unsigned short* bp = wt + brow * F_IN + bh * 32;

    float4 ax[4];
    uint4  bv[4];
    #pragma unroll
    for (int i = 0; i < 4; ++i) ax[i] = make_float4(0.f, 0.f, 0.f, 0.f);
    if (avalid) {
        #pragma unroll
        for (int i = 0; i < 4; ++i) ax[i] = ((const float4*)xp)[i];
    }
    #pragma unroll
    for (int i = 0; i < 4; ++i) bv[i] = ((const uint4*)bp)[i];

    for (int s = 0; s < 8; ++s) {
        __syncthreads();
        #pragma unroll
        for (int i = 0; i < 4; ++i) {
            ushort4 t;
            t.x = f2bf(ax[i].x); t.y = f2bf(ax[i].y);
            t.z = f2bf(ax[i].z); t.w = f2bf(ax[i].w);
            *(ushort4*)&sa[arow * 68 + aq * 16 + i * 4] = t;
        }
        #pragma unroll
        for (int i = 0; i < 4; ++i) {
            *(uint2*)&sb[brow * 68 + bh * 32 + i * 8]     = make_uint2(bv[i].x, bv[i].y);
            *(uint2*)&sb[brow * 68 + bh * 32 + i * 8 + 4] = make_uint2(bv[i].z, bv[i].w);
        }
        if (s < 7) {
            int k0n = (s + 1) * 64;
            if (avalid) {
                #pragma unroll
                for (int i = 0; i < 4; ++i) ax[i] = ((const float4*)(xp + k0n))[i];
            }
            #pragma unroll
            for (int i = 0; i < 4; ++i) bv[i] = ((const uint4*)(bp + k0n))[i];
        }
        __syncthreads();

        #pragma unroll
        for (int kc = 0; kc < 2; ++kc) {
            union { ushort4 u[2]; short8 v; } af[2];
            #pragma unroll
            for (int rt = 0; rt < 2; ++rt) {
                int abase = (wm * 32 + rt * 16 + l16) * 68 + kc * 32 + g * 8;
                af[rt].u[0] = *(ushort4*)&sa[abase];
                af[rt].u[1] = *(ushort4*)&sa[abase + 4];
            }
            #pragma unroll
            for (int nt = 0; nt < 4; ++nt) {
                union { ushort4 u[2]; short8 v; } bf;
                int bbase = (wn * 64 + nt * 16 + l16) * 68 + kc * 32 + g * 8;
                bf.u[0] = *(ushort4*)&sb[bbase];
                bf.u[1] = *(ushort4*)&sb[bbase + 4];
                #pragma unroll
                for (int rt = 0; rt < 2; ++rt)
                    acc[rt][nt] = __builtin_amdgcn_mfma_f32_16x16x32_bf16(
                        af[rt].v, bf.v, acc[rt][nt], 0, 0, 0);
            }
        }
    }

    #pragma unroll
    for (int rt = 0; rt < 2; ++rt) {
        #pragma unroll
        for (int nt = 0; nt < 4; ++nt) {
            #pragma unroll
            for (int r = 0; r < 4; ++r) {
                int row = m0 + wm * 32 + rt * 16 + g * 4 + r;
                int col = wn * 64 + nt * 16 + l16;
                if (row < N) h[(size_t)row * F_OUT + col] = f2bf(acc[rt][nt][r]);
            }
        }
    }
}

// ---------------------------------------------------------------------------
// fine_agg: one block per 32-node fine bin. Hist/scan/sort passes unchanged.
// ROUND-6 change on this kernel: gather width 8B -> 16B. Lane mapping now
// slot = lane>>4 (4 edge slots), q = lane&15 (8 feats, one uint4 per edge).
// Doubles bytes-in-flight per lane on the latency-bound random h gather at
// identical coalescing (16 lanes x 16B = same 256B row). Reduce across the
// 4 slots via shfl_xor(16)+shfl_xor(32); slot-0 lanes write 2x float4.
// ---------------------------------------------------------------------------
__global__ __launch_bounds__(256) void fine_agg(
    const unsigned short* __restrict__ h, const uint2* __restrict__ ent,
    const int* __restrict__ cursor, const float* __restrict__ bias,
    float* __restrict__ out, int N, int E,
    const int* __restrict__ ei, const float* __restrict__ ew)
{
    __shared__ unsigned ssort[CAPF];          // 8 KB
    __shared__ int lh[FBIN], lcur[FBIN];
    __shared__ int sso[FBIN + 1];

    const int b    = blockIdx.x;
    const int tid  = threadIdx.x;
    const int wave = tid >> 6;
    const int lane = tid & 63;
    const int slot = lane >> 4;               // edge slot 0..3
    const int q    = lane & 15;               // feats q*8 .. q*8+7
    const float4 bv0 = *(const float4*)&bias[q * 8];
    const float4 bv1 = *(const float4*)&bias[q * 8 + 4];
    const int raw  = cursor[b];
    const int cnt  = raw < CAPF ? raw : CAPF;
    const uint2* slab = ent + (size_t)b * CAPF;

    if (tid < FBIN) lh[tid] = 0;
    __syncthreads();

    for (int i = tid; i < cnt; i += 256)
        atomicAdd(&lh[(int)slab[i].y], 1);
    __syncthreads();

    if (wave == 0 && lane < FBIN) {
        int v = lh[lane];
        int orig = v;
        #pragma unroll
        for (int off = 1; off < FBIN; off <<= 1) {
            int t = __shfl_up(v, off);
            if (lane >= off) v += t;
        }
        sso[lane]  = v - orig;
        lcur[lane] = v - orig;
        if (lane == FBIN - 1) sso[FBIN] = v;
    }
    __syncthreads();

    if (raw <= CAPF) {
        for (int i = tid; i < cnt; i += 256) {
            uint2 e = slab[i];
            int r = atomicAdd(&lcur[(int)e.y], 1);
            ssort[r] = e.x;
        }
        __syncthreads();

        #pragma unroll 1
        for (int t = 0; t < 8; ++t) {
            int nd   = wave * 8 + t;
            int node = b * FBIN + nd;
            int s = sso[nd], e2 = sso[nd + 1];
            float4 a0 = make_float4(0.f, 0.f, 0.f, 0.f);
            float4 a1 = make_float4(0.f, 0.f, 0.f, 0.f);
            for (int i = s; i < e2; i += 16) {
                #pragma unroll
                for (int j = 0; j < 4; ++j) {
                    int idx = i + j * 4 + slot;
                    unsigned bk = 0;
                    if (idx < e2) bk = ssort[idx];
                    float wgt = bf2f(bk >> 16);
                    uint4 hv = *(const uint4*)&h[(size_t)(bk & 0xFFFF) * F_OUT + q * 8];
                    a0.x += bf2f(hv.x & 0xFFFF) * wgt;
                    a0.y += bf2f(hv.x >> 16)    * wgt;
                    a0.z += bf2f(hv.y & 0xFFFF) * wgt;
                    a0.w += bf2f(hv.y >> 16)    * wgt;
                    a1.x += bf2f(hv.z & 0xFFFF) * wgt;
                    a1.y += bf2f(hv.z >> 16)    * wgt;
                    a1.z += bf2f(hv.w & 0xFFFF) * wgt;
                    a1.w += bf2f(hv.w >> 16)    * wgt;
                }
            }
            a0.x += __shfl_xor(a0.x, 16);
            a0.y += __shfl_xor(a0.y, 16);
            a0.z += __shfl_xor(a0.z, 16);
            a0.w += __shfl_xor(a0.w, 16);
            a1.x += __shfl_xor(a1.x, 16);
            a1.y += __shfl_xor(a1.y, 16);
            a1.z += __shfl_xor(a1.z, 16);
            a1.w += __shfl_xor(a1.w, 16);
            a0.x += __shfl_xor(a0.x, 32);
            a0.y += __shfl_xor(a0.y, 32);
            a0.z += __shfl_xor(a0.z, 32);
            a0.w += __shfl_xor(a0.w, 32);
            a1.x += __shfl_xor(a1.x, 32);
            a1.y += __shfl_xor(a1.y, 32);
            a1.z += __shfl_xor(a1.z, 32);
            a1.w += __shfl_xor(a1.w, 32);
            if (slot == 0 && node < N) {
                float4 o0, o1;
                o0.x = fmaxf(a0.x + bv0.x, 0.f);
                o0.y = fmaxf(a0.y + bv0.y, 0.f);
                o0.z = fmaxf(a0.z + bv0.z, 0.f);
                o0.w = fmaxf(a0.w + bv0.w, 0.f);
                o1.x = fmaxf(a1.x + bv1.x, 0.f);
                o1.y = fmaxf(a1.y + bv1.y, 0.f);
                o1.z = fmaxf(a1.z + bv1.z, 0.f);
                o1.w = fmaxf(a1.w + bv1.w, 0.f);
                *(float4*)&out[(size_t)node * F_OUT + q * 8]     = o0;
                *(float4*)&out[(size_t)node * F_OUT + q * 8 + 4] = o1;
            }
        }
    } else {
        // slab overflow (never expected at this E/N): correct-but-slow path
        // over the raw edge list.
        #pragma unroll 1
        for (int t = 0; t < 8; ++t) {
            int nd   = wave * 8 + t;
            int node = b * FBIN + nd;
            float4 a0 = make_float4(0.f, 0.f, 0.f, 0.f);
            float4 a1 = make_float4(0.f, 0.f, 0.f, 0.f);
            for (int e = slot; e < E; e += 4) {
                if (ei[E + e] == node) {
                    float wgt = ew[e];
                    uint4 hv = *(const uint4*)&h[(size_t)ei[e] * F_OUT + q * 8];
                    a0.x += bf2f(hv.x & 0xFFFF) * wgt;
                    a0.y += bf2f(hv.x >> 16)    * wgt;
                    a0.z += bf2f(hv.y & 0xFFFF) * wgt;
                    a0.w += bf2f(hv.y >> 16)    * wgt;
                    a1.x += bf2f(hv.z & 0xFFFF) * wgt;
                    a1.y += bf2f(hv.z >> 16)    * wgt;
                    a1.z += bf2f(hv.w & 0xFFFF) * wgt;
                    a1.w += bf2f(hv.w >> 16)    * wgt;
                }
            }
            a0.x += __shfl_xor(a0.x, 16);
            a0.y += __shfl_xor(a0.y, 16);
            a0.z += __shfl_xor(a0.z, 16);
            a0.w += __shfl_xor(a0.w, 16);
            a1.x += __shfl_xor(a1.x, 16);
            a1.y += __shfl_xor(a1.y, 16);
            a1.z += __shfl_xor(a1.z, 16);
            a1.w += __shfl_xor(a1.w, 16);
            a0.x += __shfl_xor(a0.x, 32);
            a0.y += __shfl_xor(a0.y, 32);
            a0.z += __shfl_xor(a0.z, 32);
            a0.w += __shfl_xor(a0.w, 32);
            a1.x += __shfl_xor(a1.x, 32);
            a1.y += __shfl_xor(a1.y, 32);
            a1.z += __shfl_xor(a1.z, 32);
            a1.w += __shfl_xor(a1.w, 32);
            if (slot == 0 && node < N) {
                float4 o0, o1;
                o0.x = fmaxf(a0.x + bv0.x, 0.f);
                o0.y = fmaxf(a0.y + bv0.y, 0.f);
                o0.z = fmaxf(a0.z + bv0.z, 0.f);
                o0.w = fmaxf(a0.w + bv0.w, 0.f);
                o1.x = fmaxf(a1.x + bv1.x, 0.f);
                o1.y = fmaxf(a1.y + bv1.y, 0.f);
                o1.z = fmaxf(a1.z + bv1.z, 0.f);
                o1.w = fmaxf(a1.w + bv1.w, 0.f);
                *(float4*)&out[(size_t)node * F_OUT + q * 8]     = o0;
                *(float4*)&out[(size_t)node * F_OUT + q * 8 + 4] = o1;
            }
        }
    }
}

static inline size_t align256(size_t x) { return (x + 255) & ~(size_t)255; }

extern "C" void kernel_launch(void* const* d_in, const int* in_sizes, int n_in,
                              void* d_out, int out_size, void* d_ws, size_t ws_size,
                              hipStream_t stream)
{
    const float* x    = (const float*)d_in[0];   // [N, 512]
    const int*   ei   = (const int*)  d_in[1];   // [2, E] int32
    const float* ew   = (const float*)d_in[2];   // [E]
    const float* w    = (const float*)d_in[3];   // [512, 128]
    const float* bias = (const float*)d_in[4];   // [128]
    float*       out  = (float*)d_out;           // [N, 128]

    const int N  = in_sizes[0] / F_IN;           // 50000
    const int E  = in_sizes[2];                  // 1600000
    const int C2 = (N + FBIN - 1) / FBIN;        // 1563 fine bins

    // workspace layout (~38.6 MB)
    char*  ws = (char*)d_ws;
    size_t off = 0;
    unsigned short* h      = (unsigned short*)(ws + off); off += align256((size_t)N * F_OUT * 2);
    unsigned short* wt     = (unsigned short*)(ws + off); off += align256((size_t)F_OUT * F_IN * 2);
    int*            cursor = (int*)(ws + off);            off += align256((size_t)C2 * 4);
    uint2*          ent    = (uint2*)(ws + off);          off += align256((size_t)C2 * CAPF * 8);

    const int FB = (E + EPB - 1) / EPB;          // 391 fill blocks
    const int GB = (N + 63) / 64;                // 782 gemm blocks
    const int ZB = (C2 + 255) / 256;             // 7 cursor-zero blocks

    prep<<<128 + ZB, 256, 0, stream>>>(w, wt, cursor, C2);
    fill_gemm<<<FB + GB, 256, 0, stream>>>(ei, ew, cursor, ent, E, C2, FB,
                                           x, wt, h, N);
    fine_agg<<<C2, 256, 0, stream>>>(h, ent, cursor, bias, out, N, E, ei, ew);
}

// Round 7
// 252.506 us; speedup vs baseline: 3.4578x; 1.0061x over previous
//
#include <hip/hip_runtime.h>

#define F_IN  512
#define F_OUT 128
#define FBIN  32            // nodes per fine bin
#define EPB   8192          // edges per fill partition block (512 thr x 16)
#define C2MAX 1600          // max fine bins (N <= 51200)
#define CAPF  2048          // slab capacity per bin (mean ~1024, ~32 sigma headroom)

typedef __attribute__((ext_vector_type(8))) short  short8;
typedef __attribute__((ext_vector_type(4))) float  floatx4;

__device__ __forceinline__ unsigned short f2bf(float f) {
    unsigned u = __float_as_uint(f);
    return (unsigned short)((u + 0x7FFF + ((u >> 16) & 1)) >> 16);  // RNE
}
__device__ __forceinline__ float bf2f(unsigned b) {
    return __uint_as_float(b << 16);
}

// ---------------------------------------------------------------------------
// prep: blocks 0..127 transpose-convert w fp32 [512][128] -> wt bf16 [128][512];
// blocks 128.. zero the per-bin cursors.
// ---------------------------------------------------------------------------
__global__ __launch_bounds__(256) void prep(
    const float* __restrict__ w, unsigned short* __restrict__ wt,
    int* __restrict__ cursor, int C2)
{
    const int tid = threadIdx.x;
    if ((int)blockIdx.x < 128) {
        int g0 = blockIdx.x * 512 + tid;
        #pragma unroll
        for (int r = 0; r < 2; ++r) {
            int gid = g0 + r * 256;
            int n = gid >> 9, k = gid & 511;
            wt[gid] = f2bf(w[(size_t)k * F_OUT + n]);
        }
    } else {
        int c = ((int)blockIdx.x - 128) * 256 + tid;
        if (c < C2) cursor[c] = 0;
    }
}

// ---------------------------------------------------------------------------
// fill_gemm, ROUND-7: 512-thread blocks so the whole grid (196 fill + 391
// GEMM = 587 blocks, 4 resident/CU capacity = 1024 slots) runs in ONE
// generation — no block-serialization, single prologue per tile.
//   fill:  EPB 8192, 16 edges/thread register cache (same per-thread state
//          as r3); per-bin runs double (2.6 -> 5.2) -> write amp ~halved.
//   GEMM:  128x128 tile, 8 waves as 4Mx2N (wave = 32 rows x 64 cols);
//          inner loop / fragment layout / epilogue identical to r3.
//          LDS sa[128][68] + sb[128][68] = 34.8 KB.
// ---------------------------------------------------------------------------
__global__ __launch_bounds__(512, 1) void fill_gemm(
    const int* __restrict__ ei, const float* __restrict__ ew,
    int* __restrict__ cursor, uint2* __restrict__ ent, int E, int C2, int FB,
    const float* __restrict__ x, const unsigned short* __restrict__ wt,
    unsigned short* __restrict__ h, int N)
{
    __shared__ __align__(16) char smem[(128 * 68 + 128 * 68) * 2];  // 34816 B
    const int tid = threadIdx.x;

    if ((int)blockIdx.x < FB) {
        // ----- fill (r3 structure, 512 threads, EPB 8192) -----
        int* lh    = (int*)smem;            // [C2MAX]
        int* lbase = (int*)smem + C2MAX;    // [C2MAX]
        for (int c = tid; c < C2; c += 512) lh[c] = 0;
        __syncthreads();

        const int base = blockIdx.x * EPB;
        unsigned       mykey[EPB / 512];
        unsigned char  mydl[EPB / 512];
        short          mybin[EPB / 512];
        unsigned short myrank[EPB / 512];

        #pragma unroll
        for (int j = 0; j < EPB / 512; ++j) {
            int e = base + j * 512 + tid;
            mybin[j] = -1;
            if (e < E) {
                int   src = ei[e];
                int   dst = ei[E + e];
                float w   = ew[e];
                int bin = dst >> 5;                       // 32-node fine bin
                mykey[j]  = (unsigned)src | ((unsigned)f2bf(w) << 16);
                mydl[j]   = (unsigned char)(dst & (FBIN - 1));
                mybin[j]  = (short)bin;
                myrank[j] = (unsigned short)atomicAdd(&lh[bin], 1);
            }
        }
        __syncthreads();
        for (int c = tid; c < C2; c += 512)
            if (lh[c] > 0) lbase[c] = atomicAdd(&cursor[c], lh[c]);
        __syncthreads();
        #pragma unroll
        for (int j = 0; j < EPB / 512; ++j) {
            if (mybin[j] >= 0) {
                int o = lbase[mybin[j]] + myrank[j];
                if (o < CAPF)                              // overflow -> slow path covers
                    ent[(size_t)(int)mybin[j] * CAPF + o] = make_uint2(mykey[j], mydl[j]);
            }
        }
        return;
    }

    // ----- GEMM: 128x128 tile, 8 waves (4M x 2N) -----
    unsigned short* sa = (unsigned short*)smem;       // [128][68]
    unsigned short* sb = sa + 128 * 68;               // [128][68]

    const int wave = tid >> 6, lane = tid & 63;
    const int wm   = wave >> 1, wn = wave & 1;        // 4M x 2N wave grid
    const int g    = lane >> 4, l16 = lane & 15;
    const int m0   = ((int)blockIdx.x - FB) * 128;

    const int arow = tid >> 2, aq = tid & 3;          // 128 rows x 4 k-quads (A)
    const int brow = tid >> 2, bq = tid & 3;          // 128 rows x 4 k-quads (B)

    floatx4 acc[2][4];
    #pragma unroll
    for (int rt = 0; rt < 2; ++rt)
        #pragma unroll
        for (int nt = 0; nt < 4; ++nt) acc[rt][nt] = (floatx4)(0.f);

    const bool  avalid = (m0 + arow) < N;
    const float* xp = x + (size_t)(m0 + arow) * F_IN + aq * 16;
    const unsigned short* bp = wt + brow * F_IN + bq * 16;

    float4 ax[4];
    uint4  bv[2];
    #pragma unroll
    for (int i = 0; i < 4; ++i) ax[i] = make_float4(0.f, 0.f, 0.f, 0.f);
    if (avalid) {
        #pragma unroll
        for (int i = 0; i < 4; ++i) ax[i] = ((const float4*)xp)[i];
    }
    #pragma unroll
    for (int i = 0; i < 2; ++i) bv[i] = ((const uint4*)bp)[i];

    for (int s = 0; s < 8; ++s) {
        __syncthreads();
        #pragma unroll
        for (int i = 0; i < 4; ++i) {
            ushort4 t;
            t.x = f2bf(ax[i].x); t.y = f2bf(ax[i].y);
            t.z = f2bf(ax[i].z); t.w = f2bf(ax[i].w);
            *(ushort4*)&sa[arow * 68 + aq * 16 + i * 4] = t;
        }
        #pragma unroll
        for (int i = 0; i < 2; ++i) {
            *(uint2*)&sb[brow * 68 + bq * 16 + i * 8]     = make_uint2(bv[i].x, bv[i].y);
            *(uint2*)&sb[brow * 68 + bq * 16 + i * 8 + 4] = make_uint2(bv[i].z, bv[i].w);
        }
        if (s < 7) {
            int k0n = (s + 1) * 64;
            if (avalid) {
                #pragma unroll
                for (int i = 0; i < 4; ++i) ax[i] = ((const float4*)(xp + k0n))[i];
            }
            #pragma unroll
            for (int i = 0; i < 2; ++i) bv[i] = ((const uint4*)(bp + k0n))[i];
        }
        __syncthreads();

        #pragma unroll
        for (int kc = 0; kc < 2; ++kc) {
            union { ushort4 u[2]; short8 v; } af[2];
            #pragma unroll
            for (int rt = 0; rt < 2; ++rt) {
                int abase = (wm * 32 + rt * 16 + l16) * 68 + kc * 32 + g * 8;
                af[rt].u[0] = *(ushort4*)&sa[abase];
                af[rt].u[1] = *(ushort4*)&sa[abase + 4];
            }
            #pragma unroll
            for (int nt = 0; nt < 4; ++nt) {
                union { ushort4 u[2]; short8 v; } bf;
                int bbase = (wn * 64 + nt * 16 + l16) * 68 + kc * 32 + g * 8;
                bf.u[0] = *(ushort4*)&sb[bbase];
                bf.u[1] = *(ushort4*)&sb[bbase + 4];
                #pragma unroll
                for (int rt = 0; rt < 2; ++rt)
                    acc[rt][nt] = __builtin_amdgcn_mfma_f32_16x16x32_bf16(
                        af[rt].v, bf.v, acc[rt][nt], 0, 0, 0);
            }
        }
    }

    #pragma unroll
    for (int rt = 0; rt < 2; ++rt) {
        #pragma unroll
        for (int nt = 0; nt < 4; ++nt) {
            #pragma unroll
            for (int r = 0; r < 4; ++r) {
                int row = m0 + wm * 32 + rt * 16 + g * 4 + r;
                int col = wn * 64 + nt * 16 + l16;
                if (row < N) h[(size_t)row * F_OUT + col] = f2bf(acc[rt][nt][r]);
            }
        }
    }
}

// ---------------------------------------------------------------------------
// fine_agg (r6 version, unchanged): one block per 32-node fine bin.
// Two slab passes (hist+scan, node-sorted placement into LDS); wave per 8
// nodes; slot = lane>>4 (4 edge slots), q = lane&15 (8 feats, uint4 gather);
// shfl_xor(16)+shfl_xor(32) reduce; fused bias+relu 2x float4 writeout.
// ---------------------------------------------------------------------------
__global__ __launch_bounds__(256) void fine_agg(
    const unsigned short* __restrict__ h, const uint2* __restrict__ ent,
    const int* __restrict__ cursor, const float* __restrict__ bias,
    float* __restrict__ out, int N, int E,
    const int* __restrict__ ei, const float* __restrict__ ew)
{
    __shared__ unsigned ssort[CAPF];          // 8 KB
    __shared__ int lh[FBIN], lcur[FBIN];
    __shared__ int sso[FBIN + 1];

    const int b    = blockIdx.x;
    const int tid  = threadIdx.x;
    const int wave = tid >> 6;
    const int lane = tid & 63;
    const int slot = lane >> 4;               // edge slot 0..3
    const int q    = lane & 15;               // feats q*8 .. q*8+7
    const float4 bv0 = *(const float4*)&bias[q * 8];
    const float4 bv1 = *(const float4*)&bias[q * 8 + 4];
    const int raw  = cursor[b];
    const int cnt  = raw < CAPF ? raw : CAPF;
    const uint2* slab = ent + (size_t)b * CAPF;

    if (tid < FBIN) lh[tid] = 0;
    __syncthreads();

    for (int i = tid; i < cnt; i += 256)
        atomicAdd(&lh[(int)slab[i].y], 1);
    __syncthreads();

    if (wave == 0 && lane < FBIN) {
        int v = lh[lane];
        int orig = v;
        #pragma unroll
        for (int off = 1; off < FBIN; off <<= 1) {
            int t = __shfl_up(v, off);
            if (lane >= off) v += t;
        }
        sso[lane]  = v - orig;
        lcur[lane] = v - orig;
        if (lane == FBIN - 1) sso[FBIN] = v;
    }
    __syncthreads();

    if (raw <= CAPF) {
        for (int i = tid; i < cnt; i += 256) {
            uint2 e = slab[i];
            int r = atomicAdd(&lcur[(int)e.y], 1);
            ssort[r] = e.x;
        }
        __syncthreads();

        #pragma unroll 1
        for (int t = 0; t < 8; ++t) {
            int nd   = wave * 8 + t;
            int node = b * FBIN + nd;
            int s = sso[nd], e2 = sso[nd + 1];
            float4 a0 = make_float4(0.f, 0.f, 0.f, 0.f);
            float4 a1 = make_float4(0.f, 0.f, 0.f, 0.f);
            for (int i = s; i < e2; i += 16) {
                #pragma unroll
                for (int j = 0; j < 4; ++j) {
                    int idx = i + j * 4 + slot;
                    unsigned bk = 0;
                    if (idx < e2) bk = ssort[idx];
                    float wgt = bf2f(bk >> 16);
                    uint4 hv = *(const uint4*)&h[(size_t)(bk & 0xFFFF) * F_OUT + q * 8];
                    a0.x += bf2f(hv.x & 0xFFFF) * wgt;
                    a0.y += bf2f(hv.x >> 16)    * wgt;
                    a0.z += bf2f(hv.y & 0xFFFF) * wgt;
                    a0.w += bf2f(hv.y >> 16)    * wgt;
                    a1.x += bf2f(hv.z & 0xFFFF) * wgt;
                    a1.y += bf2f(hv.z >> 16)    * wgt;
                    a1.z += bf2f(hv.w & 0xFFFF) * wgt;
                    a1.w += bf2f(hv.w >> 16)    * wgt;
                }
            }
            a0.x += __shfl_xor(a0.x, 16);
            a0.y += __shfl_xor(a0.y, 16);
            a0.z += __shfl_xor(a0.z, 16);
            a0.w += __shfl_xor(a0.w, 16);
            a1.x += __shfl_xor(a1.x, 16);
            a1.y += __shfl_xor(a1.y, 16);
            a1.z += __shfl_xor(a1.z, 16);
            a1.w += __shfl_xor(a1.w, 16);
            a0.x += __shfl_xor(a0.x, 32);
            a0.y += __shfl_xor(a0.y, 32);
            a0.z += __shfl_xor(a0.z, 32);
            a0.w += __shfl_xor(a0.w, 32);
            a1.x += __shfl_xor(a1.x, 32);
            a1.y += __shfl_xor(a1.y, 32);
            a1.z += __shfl_xor(a1.z, 32);
            a1.w += __shfl_xor(a1.w, 32);
            if (slot == 0 && node < N) {
                float4 o0, o1;
                o0.x = fmaxf(a0.x + bv0.x, 0.f);
                o0.y = fmaxf(a0.y + bv0.y, 0.f);
                o0.z = fmaxf(a0.z + bv0.z, 0.f);
                o0.w = fmaxf(a0.w + bv0.w, 0.f);
                o1.x = fmaxf(a1.x + bv1.x, 0.f);
                o1.y = fmaxf(a1.y + bv1.y, 0.f);
                o1.z = fmaxf(a1.z + bv1.z, 0.f);
                o1.w = fmaxf(a1.w + bv1.w, 0.f);
                *(float4*)&out[(size_t)node * F_OUT + q * 8]     = o0;
                *(float4*)&out[(size_t)node * F_OUT + q * 8 + 4] = o1;
            }
        }
    } else {
        // slab overflow (never expected at this E/N): correct-but-slow path
        // over the raw edge list.
        #pragma unroll 1
        for (int t = 0; t < 8; ++t) {
            int nd   = wave * 8 + t;
            int node = b * FBIN + nd;
            float4 a0 = make_float4(0.f, 0.f, 0.f, 0.f);
            float4 a1 = make_float4(0.f, 0.f, 0.f, 0.f);
            for (int e = slot; e < E; e += 4) {
                if (ei[E + e] == node) {
                    float wgt = ew[e];
                    uint4 hv = *(const uint4*)&h[(size_t)ei[e] * F_OUT + q * 8];
                    a0.x += bf2f(hv.x & 0xFFFF) * wgt;
                    a0.y += bf2f(hv.x >> 16)    * wgt;
                    a0.z += bf2f(hv.y & 0xFFFF) * wgt;
                    a0.w += bf2f(hv.y >> 16)    * wgt;
                    a1.x += bf2f(hv.z & 0xFFFF) * wgt;
                    a1.y += bf2f(hv.z >> 16)    * wgt;
                    a1.z += bf2f(hv.w & 0xFFFF) * wgt;
                    a1.w += bf2f(hv.w >> 16)    * wgt;
                }
            }
            a0.x += __shfl_xor(a0.x, 16);
            a0.y += __shfl_xor(a0.y, 16);
            a0.z += __shfl_xor(a0.z, 16);
            a0.w += __shfl_xor(a0.w, 16);
            a1.x += __shfl_xor(a1.x, 16);
            a1.y += __shfl_xor(a1.y, 16);
            a1.z += __shfl_xor(a1.z, 16);
            a1.w += __shfl_xor(a1.w, 16);
            a0.x += __shfl_xor(a0.x, 32);
            a0.y += __shfl_xor(a0.y, 32);
            a0.z += __shfl_xor(a0.z, 32);
            a0.w += __shfl_xor(a0.w, 32);
            a1.x += __shfl_xor(a1.x, 32);
            a1.y += __shfl_xor(a1.y, 32);
            a1.z += __shfl_xor(a1.z, 32);
            a1.w += __shfl_xor(a1.w, 32);
            if (slot == 0 && node < N) {
                float4 o0, o1;
                o0.x = fmaxf(a0.x + bv0.x, 0.f);
                o0.y = fmaxf(a0.y + bv0.y, 0.f);
                o0.z = fmaxf(a0.z + bv0.z, 0.f);
                o0.w = fmaxf(a0.w + bv0.w, 0.f);
                o1.x = fmaxf(a1.x + bv1.x, 0.f);
                o1.y = fmaxf(a1.y + bv1.y, 0.f);
                o1.z = fmaxf(a1.z + bv1.z, 0.f);
                o1.w = fmaxf(a1.w + bv1.w, 0.f);
                *(float4*)&out[(size_t)node * F_OUT + q * 8]     = o0;
                *(float4*)&out[(size_t)node * F_OUT + q * 8 + 4] = o1;
            }
        }
    }
}

static inline size_t align256(size_t x) { return (x + 255) & ~(size_t)255; }

extern "C" void kernel_launch(void* const* d_in, const int* in_sizes, int n_in,
                              void* d_out, int out_size, void* d_ws, size_t ws_size,
                              hipStream_t stream)
{
    const float* x    = (const float*)d_in[0];   // [N, 512]
    const int*   ei   = (const int*)  d_in[1];   // [2, E] int32
    const float* ew   = (const float*)d_in[2];   // [E]
    const float* w    = (const float*)d_in[3];   // [512, 128]
    const float* bias = (const float*)d_in[4];   // [128]
    float*       out  = (float*)d_out;           // [N, 128]

    const int N  = in_sizes[0] / F_IN;           // 50000
    const int E  = in_sizes[2];                  // 1600000
    const int C2 = (N + FBIN - 1) / FBIN;        // 1563 fine bins

    // workspace layout (~38.6 MB)
    char*  ws = (char*)d_ws;
    size_t off = 0;
    unsigned short* h      = (unsigned short*)(ws + off); off += align256((size_t)N * F_OUT * 2);
    unsigned short* wt     = (unsigned short*)(ws + off); off += align256((size_t)F_OUT * F_IN * 2);
    int*            cursor = (int*)(ws + off);            off += align256((size_t)C2 * 4);
    uint2*          ent    = (uint2*)(ws + off);          off += align256((size_t)C2 * CAPF * 8);

    const int FB = (E + EPB - 1) / EPB;          // 196 fill blocks
    const int GB = (N + 127) / 128;              // 391 gemm blocks
    const int ZB = (C2 + 255) / 256;             // 7 cursor-zero blocks

    prep<<<128 + ZB, 256, 0, stream>>>(w, wt, cursor, C2);
    fill_gemm<<<FB + GB, 512, 0, stream>>>(ei, ew, cursor, ent, E, C2, FB,
                                           x, wt, h, N);
    fine_agg<<<C2, 256, 0, stream>>>(h, ent, cursor, bias, out, N, E, ei, ew);
}